// Round 2
// baseline (60.728 us; speedup 1.0000x reference)
//
#include <hip/hip_runtime.h>

// Persistence image: out[b,d,i,j] = sum_p w_p * exp(-50*((x_i-birth_p)^2 + (y_j-pers_p)^2))
// with w_p = max(pers_p, 0), pers_p = death_p - birth_p, x_i = i/19, y_j = j/19.
// Separable Gaussian: per point build gxw[i] = w*exp(-50*(x_i-b)^2) and
// gy[j] = exp(-50*(y_j-p)^2) in LDS, then cells accumulate gxw[i]*gy[j].
//
// Two kernels, zero atomics, zero memset:
//   A) 768 blocks (96 bd x 8 splits) -> partials in d_ws (plain stores)
//   B) 150 blocks sum the 8 partials per cell -> d_out (plain stores)

#define RX 20
#define RY 20
#define NCELL (RX * RY)
#define SPLIT 8        // blocks per (b,d); 96*8 = 768 blocks -> ~3 blocks/CU
#define CHUNK 256      // points per block (one per thread in phase 1)
#define STRIDE 22      // padded LDS row stride in floats: 88B = 8B-aligned, gcd(22,32)=2

__global__ __launch_bounds__(256) void pimg_partial(const float2* __restrict__ pd,
                                                    float* __restrict__ partial) {
    __shared__ __attribute__((aligned(16))) float s_gxw[CHUNK * STRIDE];
    __shared__ __attribute__((aligned(16))) float s_gy[CHUNK * STRIDE];
    __shared__ int s_wave_cnt[4];

    const int tid   = threadIdx.x;
    const int bd    = blockIdx.x / SPLIT;
    const int chunk = blockIdx.x % SPLIT;
    const int pbase = bd * 2048 + chunk * CHUNK;

    // ---- Phase 1: load one point per thread, compact active (pers>0) into LDS tables
    float2 p2  = pd[pbase + tid];        // (birth, death), coalesced 8B/lane
    float birth = p2.x;
    float pers  = p2.y - p2.x;
    bool active = pers > 0.0f;

    unsigned long long mask = __ballot(active);
    int lane = tid & 63;
    int wid  = tid >> 6;
    int rank = __popcll(mask & ((1ull << lane) - 1ull));
    if (lane == 0) s_wave_cnt[wid] = __popcll(mask);
    __syncthreads();

    int offset = 0;
    #pragma unroll
    for (int w = 0; w < 4; ++w)
        if (w < wid) offset += s_wave_cnt[w];
    int total = s_wave_cnt[0] + s_wave_cnt[1] + s_wave_cnt[2] + s_wave_cnt[3];

    if (active) {
        int slot = offset + rank;
        #pragma unroll
        for (int i = 0; i < RX; ++i) {
            float xi = i * (1.0f / 19.0f);
            float dx = xi - birth;
            float dy = xi - pers;
            s_gxw[slot * STRIDE + i] = pers * __expf(-50.0f * dx * dx);
            s_gy [slot * STRIDE + i] =        __expf(-50.0f * dy * dy);
        }
    }
    __syncthreads();

    // ---- Phase 2: threads 0..199 each own cells (i, j0) and (i, j0+1)
    if (tid < 200) {
        int i  = tid / 10;
        int j0 = (tid % 10) * 2;
        float acc0 = 0.0f, acc1 = 0.0f;
        #pragma unroll 4
        for (int p = 0; p < total; ++p) {
            float  gx = s_gxw[p * STRIDE + i];
            float2 gy = *(const float2*)&s_gy[p * STRIDE + j0];
            acc0 = fmaf(gx, gy.x, acc0);
            acc1 = fmaf(gx, gy.y, acc1);
        }
        float2 v = make_float2(acc0, acc1);
        *(float2*)&partial[blockIdx.x * NCELL + i * RY + j0] = v;  // plain store
    }
}

// Sum SPLIT partials per output cell. n_out = n_bd * 400.
__global__ __launch_bounds__(256) void pimg_reduce(const float* __restrict__ partial,
                                                   float* __restrict__ out,
                                                   int n_out) {
    int o = blockIdx.x * blockDim.x + threadIdx.x;
    if (o >= n_out) return;
    int bd   = o / NCELL;
    int cell = o - bd * NCELL;
    const float* p = partial + (size_t)(bd * SPLIT) * NCELL + cell;
    float s = 0.0f;
    #pragma unroll
    for (int k = 0; k < SPLIT; ++k)
        s += p[k * NCELL];
    out[o] = s;
}

extern "C" void kernel_launch(void* const* d_in, const int* in_sizes, int n_in,
                              void* d_out, int out_size, void* d_ws, size_t ws_size,
                              hipStream_t stream) {
    const float2* pd = (const float2*)d_in[0];
    float* out = (float*)d_out;
    float* ws  = (float*)d_ws;
    int n_bd  = in_sizes[0] / (2048 * 2);   // 32*3 = 96
    int n_out = n_bd * NCELL;               // 38400

    pimg_partial<<<dim3(n_bd * SPLIT), dim3(256), 0, stream>>>(pd, ws);
    pimg_reduce <<<dim3((n_out + 255) / 256), dim3(256), 0, stream>>>(ws, out, n_out);
}

// Round 3
// 59.897 us; speedup vs baseline: 1.0139x; 1.0139x over previous
//
#include <hip/hip_runtime.h>

// Persistence image: out[b,d,i,j] = sum_p w_p * exp(-50*((x_i-birth_p)^2 + (y_j-pers_p)^2))
// with w_p = max(pers_p, 0), pers_p = death_p - birth_p, x_i = i/19, y_j = j/19.
// Separable Gaussian: per point build gxw[i] = w*exp(-50*(x_i-b)^2) and
// gy[j] = exp(-50*(y_j-p)^2) in LDS, then cells accumulate gxw[i]*gy[j].
//
// R3: phase-2 tiled 2x4 cells/thread (50 threads, 1 wave) -> 1 b64 + 1 b128
// LDS read per point (was 4 waves x (b32+b64)); STRIDE 24 for 16B alignment;
// phase-1 tables built in registers, stored with 5x ds_write_b128 per table.

#define RX 20
#define RY 20
#define NCELL (RX * RY)
#define SPLIT 8        // blocks per (b,d); 96*8 = 768 blocks -> ~3 blocks/CU
#define CHUNK 256      // points per block (one per thread in phase 1)
#define STRIDE 24      // floats; 96B row -> 16B-aligned slots for b128 LDS ops

__global__ __launch_bounds__(256) void pimg_partial(const float2* __restrict__ pd,
                                                    float* __restrict__ partial) {
    __shared__ __attribute__((aligned(16))) float s_gxw[CHUNK * STRIDE];
    __shared__ __attribute__((aligned(16))) float s_gy[CHUNK * STRIDE];
    __shared__ int s_wave_cnt[4];

    const int tid   = threadIdx.x;
    const int bd    = blockIdx.x / SPLIT;
    const int chunk = blockIdx.x % SPLIT;
    const int pbase = bd * 2048 + chunk * CHUNK;

    // ---- Phase 1: load one point per thread, compact active (pers>0) into LDS tables
    float2 p2  = pd[pbase + tid];        // (birth, death), coalesced 8B/lane
    float birth = p2.x;
    float pers  = p2.y - p2.x;
    bool active = pers > 0.0f;

    unsigned long long mask = __ballot(active);
    int lane = tid & 63;
    int wid  = tid >> 6;
    int rank = __popcll(mask & ((1ull << lane) - 1ull));
    if (lane == 0) s_wave_cnt[wid] = __popcll(mask);
    __syncthreads();

    int offset = 0;
    #pragma unroll
    for (int w = 0; w < 4; ++w)
        if (w < wid) offset += s_wave_cnt[w];
    int total = s_wave_cnt[0] + s_wave_cnt[1] + s_wave_cnt[2] + s_wave_cnt[3];

    if (active) {
        int slot = offset + rank;
        float gx[RX], gy[RX];
        #pragma unroll
        for (int i = 0; i < RX; ++i) {
            float xi = i * (1.0f / 19.0f);
            float dx = xi - birth;
            float dy = xi - pers;
            gx[i] = pers * __expf(-50.0f * dx * dx);
            gy[i] =        __expf(-50.0f * dy * dy);
        }
        float4* dx4 = (float4*)&s_gxw[slot * STRIDE];
        float4* dy4 = (float4*)&s_gy [slot * STRIDE];
        #pragma unroll
        for (int k = 0; k < 5; ++k) {
            dx4[k] = make_float4(gx[4*k], gx[4*k+1], gx[4*k+2], gx[4*k+3]);
            dy4[k] = make_float4(gy[4*k], gy[4*k+1], gy[4*k+2], gy[4*k+3]);
        }
    }
    __syncthreads();

    // ---- Phase 2: threads 0..49 each own a 2x4 cell tile (rows i0,i0+1; cols j0..j0+3)
    if (tid < 50) {
        int i0 = (tid / 5) * 2;
        int j0 = (tid % 5) * 4;
        float a00=0,a01=0,a02=0,a03=0, a10=0,a11=0,a12=0,a13=0;
        #pragma unroll 4
        for (int p = 0; p < total; ++p) {
            float2 gx = *(const float2*)&s_gxw[p * STRIDE + i0];
            float4 gy = *(const float4*)&s_gy [p * STRIDE + j0];
            a00 = fmaf(gx.x, gy.x, a00);  a01 = fmaf(gx.x, gy.y, a01);
            a02 = fmaf(gx.x, gy.z, a02);  a03 = fmaf(gx.x, gy.w, a03);
            a10 = fmaf(gx.y, gy.x, a10);  a11 = fmaf(gx.y, gy.y, a11);
            a12 = fmaf(gx.y, gy.z, a12);  a13 = fmaf(gx.y, gy.w, a13);
        }
        float* base = partial + (size_t)blockIdx.x * NCELL;
        *(float4*)&base[(i0    ) * RY + j0] = make_float4(a00, a01, a02, a03);
        *(float4*)&base[(i0 + 1) * RY + j0] = make_float4(a10, a11, a12, a13);
    }
}

// Sum SPLIT partials per output cell. n_out = n_bd * 400.
__global__ __launch_bounds__(256) void pimg_reduce(const float* __restrict__ partial,
                                                   float* __restrict__ out,
                                                   int n_out) {
    int o = blockIdx.x * blockDim.x + threadIdx.x;
    if (o >= n_out) return;
    int bd   = o / NCELL;
    int cell = o - bd * NCELL;
    const float* p = partial + (size_t)(bd * SPLIT) * NCELL + cell;
    float s = 0.0f;
    #pragma unroll
    for (int k = 0; k < SPLIT; ++k)
        s += p[k * NCELL];
    out[o] = s;
}

extern "C" void kernel_launch(void* const* d_in, const int* in_sizes, int n_in,
                              void* d_out, int out_size, void* d_ws, size_t ws_size,
                              hipStream_t stream) {
    const float2* pd = (const float2*)d_in[0];
    float* out = (float*)d_out;
    float* ws  = (float*)d_ws;
    int n_bd  = in_sizes[0] / (2048 * 2);   // 32*3 = 96
    int n_out = n_bd * NCELL;               // 38400

    pimg_partial<<<dim3(n_bd * SPLIT), dim3(256), 0, stream>>>(pd, ws);
    pimg_reduce <<<dim3((n_out + 255) / 256), dim3(256), 0, stream>>>(ws, out, n_out);
}